// Round 3
// baseline (154.653 us; speedup 1.0000x reference)
//
#include <hip/hip_runtime.h>
#include <hip/hip_bf16.h>
#include <cstdint>
#include <cstddef>
#include <math.h>

#define B_SZ 512
#define E_SZ 512
#define C_SZ 70722
#define PAD_C 70784          // 553 * 128
#define M_MARGIN 0.4f
#define H_CONST 0.333f
#define S_CONST 64.0f
#define EPS_F 1e-3f
#define PI_F 3.14159265358979323846f

typedef __attribute__((ext_vector_type(8))) short short8;
typedef __attribute__((ext_vector_type(4))) float f32x4;

// ---------------- helpers ----------------

__device__ __forceinline__ unsigned short f2bf(float x) {
  __hip_bfloat16 h = __float2bfloat16(x);
  unsigned short u;
  __builtin_memcpy(&u, &h, 2);
  return u;
}

__device__ __forceinline__ void gload_lds16(const void* g, void* l) {
  __builtin_amdgcn_global_load_lds(
      (const __attribute__((address_space(1))) unsigned int*)g,
      (__attribute__((address_space(3))) unsigned int*)l, 16, 0, 0);
}

// XOR swizzle (byte units, bits 4-6) for 128B-row LDS tiles (fallback path)
__device__ __forceinline__ int swzb(int rc) {
  return (((rc & 7) ^ ((rc >> 2) & 7)) << 4);
}

// ---------------- kernel 1: per-row margin stats ----------------
__global__ void k_stats(const float* __restrict__ norms, const int* __restrict__ label,
                        float* __restrict__ ga, float* __restrict__ gadd) {
  __shared__ float sn[B_SZ];
  __shared__ int lab[B_SZ];
  __shared__ float redA[8], redB[8];
  __shared__ float sh_std;

  int t = threadIdx.x;
  float v = norms[t];
  v = fminf(fmaxf(v, 1e-3f), 100.0f);
  sn[t] = v;
  lab[t] = label[t];

  float s1 = v, s2 = v * v;
  #pragma unroll
  for (int o = 32; o > 0; o >>= 1) {
    s1 += __shfl_down(s1, o);
    s2 += __shfl_down(s2, o);
  }
  if ((t & 63) == 0) { redA[t >> 6] = s1; redB[t >> 6] = s2; }
  __syncthreads();
  if (t == 0) {
    float a = 0.f, b = 0.f;
    #pragma unroll
    for (int i = 0; i < 8; ++i) { a += redA[i]; b += redB[i]; }
    float mean = a / (float)B_SZ;
    float var = (b - (float)B_SZ * mean * mean) / (float)(B_SZ - 1);
    sh_std = sqrtf(fmaxf(var, 0.f));
  }
  __syncthreads();
  float stdv = sh_std;

  int myl = lab[t];
  float s = 0.f, cnt = 0.f;
  for (int j = 0; j < B_SZ; ++j) {
    bool m = (lab[j] == myl);
    s += m ? sn[j] : 0.f;
    cnt += m ? 1.f : 0.f;
  }
  float gm = s / fmaxf(cnt, 1.f);
  float ms = (v - gm) / (stdv + EPS_F) * H_CONST;
  ms = fminf(fmaxf(ms, -1.f), 1.f);
  ga[t] = -M_MARGIN * ms;
  gadd[t] = M_MARGIN + M_MARGIN * ms;
}

// ---------------- kernel 2: emb fp32 -> bf16 ----------------
__global__ void k_cvtA(const float* __restrict__ emb, unsigned short* __restrict__ abf) {
  int i = (blockIdx.x * 256 + threadIdx.x) * 4;
  float4 f = *(const float4*)(emb + i);
  unsigned short u0 = f2bf(f.x), u1 = f2bf(f.y), u2 = f2bf(f.z), u3 = f2bf(f.w);
  unsigned long long pk = (unsigned long long)u0 | ((unsigned long long)u1 << 16) |
                          ((unsigned long long)u2 << 32) | ((unsigned long long)u3 << 48);
  *(unsigned long long*)(abf + i) = pk;
}

// ---------------- kernel 3: fused colnorm + transpose-convert ----------------
__global__ void k_prep(const float* __restrict__ K, float* __restrict__ invn,
                       unsigned short* __restrict__ BT) {
  __shared__ float T[64 * 64];        // [k][c^((k&7)<<2)]
  __shared__ float part[16][64];

  const int t = threadIdx.x;
  const int c0 = blockIdx.x * 64;
  const int cl = t & 15;
  const int kr = t >> 4;
  const int cq = t >> 2;
  const int kq = t & 3;
  const bool full = (c0 + 64 <= C_SZ);

  float ss0 = 0.f, ss1 = 0.f, ss2 = 0.f, ss3 = 0.f;

  for (int ch = 0; ch < 8; ++ch) {
    if (ch) __syncthreads();
    #pragma unroll
    for (int i = 0; i < 4; ++i) {
      int klo = kr + i * 16;
      int kg = ch * 64 + klo;
      float4 f;
      if (full) {
        f = *(const float4*)(K + (size_t)kg * C_SZ + c0 + cl * 4);
      } else {
        float* fp = (float*)&f;
        #pragma unroll
        for (int j = 0; j < 4; ++j) {
          int c = c0 + cl * 4 + j;
          fp[j] = (c < C_SZ) ? K[(size_t)kg * C_SZ + c] : 0.f;
        }
      }
      ss0 += f.x * f.x; ss1 += f.y * f.y; ss2 += f.z * f.z; ss3 += f.w * f.w;
      int swz = (klo & 7) << 2;
      *(float4*)&T[klo * 64 + ((cl * 4) ^ swz)] = f;
    }
    __syncthreads();
    #pragma unroll
    for (int sub = 0; sub < 2; ++sub) {
      int k8 = sub * 32 + kq * 8;
      short8 v;
      #pragma unroll
      for (int i = 0; i < 8; ++i) {
        v[i] = (short)f2bf(T[(k8 + i) * 64 + (cq ^ (i << 2))]);
      }
      *(short8*)(BT + ((size_t)(c0 + cq) << 9) + ch * 64 + k8) = v;
    }
  }

  __syncthreads();
  part[kr][cl * 4 + 0] = ss0;
  part[kr][cl * 4 + 1] = ss1;
  part[kr][cl * 4 + 2] = ss2;
  part[kr][cl * 4 + 3] = ss3;
  __syncthreads();
  if (t < 64) {
    int c = c0 + t;
    float s = 0.f;
    #pragma unroll
    for (int r = 0; r < 16; ++r) s += part[r][t];
    invn[c] = (c < C_SZ) ? rsqrtf(s) : 0.f;
  }
}

// ---------------- kernel 4: pipelined GEMM + epilogue ----------------
// 128x128 tile, BK=32, 16 K-steps, 3 LDS buffers, 2-deep prefetch, counted vmcnt.
__launch_bounds__(256)
__global__ void k_gemm_fast(const unsigned short* __restrict__ Abf,  // [512][512]
                            const unsigned short* __restrict__ BT,   // [PAD_C][512]
                            const float* __restrict__ invn,          // [PAD_C]
                            const int* __restrict__ label,
                            const float* __restrict__ ga,
                            const float* __restrict__ gadd,
                            float* __restrict__ out) {
  // 64-byte rows (32 bf16). Chunk-permuted: LDS[r][p] = global[r][p ^ ((r>>1)&3)]
  __shared__ __align__(16) unsigned short As[3][128 * 32];
  __shared__ __align__(16) unsigned short Bs[3][128 * 32];
  __shared__ int lab_s[128];
  __shared__ float ga_s[128], gadd_s[128];

  const int tid = threadIdx.x;
  const int nwg = gridDim.x;
  int bid = blockIdx.x;

  // bijective XCD swizzle (m204)
  int q = nwg >> 3, r8 = nwg & 7;
  int xcd = bid & 7, lb = bid >> 3;
  int wg = (xcd < r8 ? xcd * (q + 1) : r8 * (q + 1) + (xcd - r8) * q) + lb;

  const int mt = wg & 3;
  const int nt = wg >> 2;
  const int row0 = mt << 7;
  const int col0 = nt << 7;

  if (tid < 128) {
    int gr = row0 + tid;
    lab_s[tid] = label[gr];
    ga_s[tid] = ga[gr];
    gadd_s[tid] = gadd[gr];
  }

  const int wid = tid >> 6, lane = tid & 63;
  const int wr = wid >> 1, wc = wid & 1;

  // ---- staging addresses (per-lane global source, pre-swizzled) ----
  const int lr = lane >> 2;          // row within 16-row DMA stripe
  const int lc = lane & 3;           // 16B chunk position
  const int rA0 = wid * 32 + lr;          // local rows [wid*32, +16)
  const int rA1 = wid * 32 + 16 + lr;     // local rows [wid*32+16, +16)
  const int sA0 = lc ^ ((rA0 >> 1) & 3);
  const int sA1 = lc ^ ((rA1 >> 1) & 3);
  const unsigned short* srcA0 = Abf + (size_t)(row0 + rA0) * 512 + sA0 * 8;
  const unsigned short* srcA1 = Abf + (size_t)(row0 + rA1) * 512 + sA1 * 8;
  const unsigned short* srcB0 = BT + (size_t)(col0 + rA0) * 512 + sA0 * 8;
  const unsigned short* srcB1 = BT + (size_t)(col0 + rA1) * 512 + sA1 * 8;
  char* const dA0 = (char*)&As[0][0] + (wid * 32) * 64;          // wave-uniform
  char* const dB0 = (char*)&Bs[0][0] + (wid * 32) * 64;

  // ---- fragment LDS byte offsets (relative to buffer base) ----
  int offA[4], offB[4];
  #pragma unroll
  for (int m = 0; m < 4; ++m) {
    int row = wr * 64 + m * 16 + (lane & 15);
    offA[m] = row * 64 + (((lane >> 4) ^ ((row >> 1) & 3)) << 4);
  }
  #pragma unroll
  for (int n = 0; n < 4; ++n) {
    int cr = wc * 64 + n * 16 + (lane & 15);
    offB[n] = cr * 64 + (((lane >> 4) ^ ((cr >> 1) & 3)) << 4);
  }

  f32x4 acc[4][4];
  #pragma unroll
  for (int m = 0; m < 4; ++m)
    #pragma unroll
    for (int n = 0; n < 4; ++n)
      acc[m][n] = f32x4{0.f, 0.f, 0.f, 0.f};

#define STAGE(nb)                                                        \
  {                                                                      \
    char* dA = dA0 + (nb) * 8192;                                        \
    char* dB = dB0 + (nb) * 8192;                                        \
    gload_lds16(srcA0, dA);                                              \
    gload_lds16(srcA1, dA + 1024);                                       \
    gload_lds16(srcB0, dB);                                              \
    gload_lds16(srcB1, dB + 1024);                                       \
    srcA0 += 32; srcA1 += 32; srcB0 += 32; srcB1 += 32;                  \
  }

  // prologue: stage K-tiles 0,1 into buffers 0,1 (8 loads in flight)
  STAGE(0)
  STAGE(1)

  int bs = 0;
  for (int kt = 0; kt < 16; ++kt) {
    // my K-tile kt loads done (allow the 4 newer ones to stay in flight)
    if (kt < 15) asm volatile("s_waitcnt vmcnt(4)" ::: "memory");
    else         asm volatile("s_waitcnt vmcnt(0)" ::: "memory");
    __builtin_amdgcn_s_barrier();       // everyone's kt staged; everyone done reading buf[(kt+2)%3]
    __builtin_amdgcn_sched_barrier(0);

    if (kt < 14) {
      int nb = bs + 2; if (nb >= 3) nb -= 3;
      STAGE(nb)
    }

    const char* pA = (const char*)&As[0][0] + bs * 8192;
    const char* pB = (const char*)&Bs[0][0] + bs * 8192;
    short8 a[4], b[4];
    #pragma unroll
    for (int m = 0; m < 4; ++m) a[m] = *(const short8*)(pA + offA[m]);
    #pragma unroll
    for (int n = 0; n < 4; ++n) b[n] = *(const short8*)(pB + offB[n]);

    asm volatile("s_waitcnt lgkmcnt(0)" ::: "memory");
    __builtin_amdgcn_sched_barrier(0);

    __builtin_amdgcn_s_setprio(1);
    #pragma unroll
    for (int m = 0; m < 4; ++m)
      #pragma unroll
      for (int n = 0; n < 4; ++n)
        acc[m][n] = __builtin_amdgcn_mfma_f32_16x16x32_bf16(a[m], b[n], acc[m][n], 0, 0, 0);
    __builtin_amdgcn_s_setprio(0);

    bs = (bs == 2) ? 0 : bs + 1;
  }
#undef STAGE

  // ---- epilogue: scale by invn, clip, margin on label column ----
  float invc[4];
  #pragma unroll
  for (int n = 0; n < 4; ++n)
    invc[n] = invn[col0 + wc * 64 + n * 16 + (lane & 15)];

  #pragma unroll
  for (int m = 0; m < 4; ++m) {
    int rl0 = wr * 64 + m * 16 + ((lane >> 4) << 2);
    #pragma unroll
    for (int n = 0; n < 4; ++n) {
      int cl = wc * 64 + n * 16 + (lane & 15);
      int gc = col0 + cl;
      if (gc >= C_SZ) continue;
      #pragma unroll
      for (int r = 0; r < 4; ++r) {
        int rl = rl0 + r;
        float v = acc[m][n][r] * invc[n];
        v = fminf(fmaxf(v, -1.f + EPS_F), 1.f - EPS_F);
        float res = v * S_CONST;
        if (gc == lab_s[rl]) {
          float th = acosf(v) + ga_s[rl];
          th = fminf(fmaxf(th, EPS_F), PI_F - EPS_F);
          res = (cosf(th) - gadd_s[rl]) * S_CONST;
        }
        out[(size_t)(row0 + rl) * C_SZ + gc] = res;
      }
    }
  }
}

// ================= fallback path (round-1, known-good) =================

__global__ void k_colnorm(const float* __restrict__ K, float* __restrict__ inv) {
  __shared__ float part[4][64];
  int cl = threadIdx.x & 63;
  int rq = threadIdx.x >> 6;
  int c = blockIdx.x * 64 + cl;
  float s = 0.f;
  if (c < C_SZ) {
    const float* p = K + (size_t)rq * 128 * C_SZ + c;
    #pragma unroll 8
    for (int r = 0; r < 128; ++r) {
      float x = p[(size_t)r * C_SZ];
      s += x * x;
    }
  }
  part[rq][cl] = s;
  __syncthreads();
  if (threadIdx.x < 64) {
    int c2 = blockIdx.x * 64 + threadIdx.x;
    if (c2 < C_SZ) {
      float tt = part[0][threadIdx.x] + part[1][threadIdx.x] +
                 part[2][threadIdx.x] + part[3][threadIdx.x];
      inv[c2] = rsqrtf(tt);
    } else if (c2 < PAD_C) {
      inv[c2] = 0.f;
    }
  }
}

__launch_bounds__(256)
__global__ void k_gemm_fb(const unsigned short* __restrict__ Abf,
                          const float* __restrict__ Kmat,
                          const float* __restrict__ invn,
                          const int* __restrict__ label,
                          const float* __restrict__ ga,
                          const float* __restrict__ gadd,
                          float* __restrict__ out) {
  __shared__ __align__(16) unsigned short As[128 * 64];
  __shared__ __align__(16) unsigned short Bs[128 * 64];
  __shared__ int lab_s[128];
  __shared__ float ga_s[128], gadd_s[128];

  const int tid = threadIdx.x;
  const int nwg = gridDim.x;
  int bid = blockIdx.x;
  int q = nwg >> 3, r8 = nwg & 7;
  int xcd = bid & 7, lb = bid >> 3;
  int wg = (xcd < r8 ? xcd * (q + 1) : r8 * (q + 1) + (xcd - r8) * q) + lb;
  const int mt = wg & 3;
  const int nt = wg >> 2;
  const int row0 = mt << 7;
  const int col0 = nt << 7;

  if (tid < 128) {
    int gr = row0 + tid;
    lab_s[tid] = label[gr];
    ga_s[tid] = ga[gr];
    gadd_s[tid] = gadd[gr];
  }

  const int wid = tid >> 6, lane = tid & 63;
  const int wr = wid >> 1, wc = wid & 1;
  const int cc = tid & 31;
  const int kq = tid >> 5;
  const bool edge = (col0 + 128 > C_SZ);
  float4 inv4 = *(const float4*)(invn + col0 + cc * 4);

  f32x4 acc[4][4];
  #pragma unroll
  for (int m = 0; m < 4; ++m)
    #pragma unroll
    for (int n = 0; n < 4; ++n)
      acc[m][n] = f32x4{0.f, 0.f, 0.f, 0.f};

  const float* Bg = Kmat + col0;

  for (int kt = 0; kt < 8; ++kt) {
    const int kb = kt * 64;
    if (kt) __syncthreads();

    #pragma unroll
    for (int rr = 0; rr < 4; ++rr) {
      int rowblk = wid * 32 + rr * 8;
      int r = rowblk + (lane >> 3);
      int s = (lane & 7) ^ ((r & 7) ^ ((r >> 2) & 7));
      gload_lds16(Abf + (size_t)(row0 + r) * 512 + kb + s * 8, (char*)As + rowblk * 128);
    }

    #pragma unroll
    for (int i = 0; i < 4; ++i) {
      int k = (kq + i * 8) * 2;
      const float* g0 = Bg + (size_t)(kb + k) * C_SZ + cc * 4;
      const float* g1 = g0 + C_SZ;
      float x0[4], x1[4];
      if (!edge) {
        float4 f0 = *(const float4*)g0;
        float4 f1 = *(const float4*)g1;
        x0[0]=f0.x; x0[1]=f0.y; x0[2]=f0.z; x0[3]=f0.w;
        x1[0]=f1.x; x1[1]=f1.y; x1[2]=f1.z; x1[3]=f1.w;
      } else {
        #pragma unroll
        for (int j = 0; j < 4; ++j) {
          int gc = col0 + cc * 4 + j;
          x0[j] = (gc < C_SZ) ? g0[j] : 0.f;
          x1[j] = (gc < C_SZ) ? g1[j] : 0.f;
        }
      }
      #pragma unroll
      for (int j = 0; j < 4; ++j) {
        int c = cc * 4 + j;
        float iv = ((const float*)&inv4)[j];
        unsigned int pk = ((unsigned int)f2bf(x1[j] * iv) << 16) | (unsigned int)f2bf(x0[j] * iv);
        int byte = (c * 128 + k * 2) ^ swzb(c);
        *(unsigned int*)((char*)Bs + byte) = pk;
      }
    }

    __syncthreads();

    #pragma unroll
    for (int ks = 0; ks < 2; ++ks) {
      short8 a[4], b[4];
      #pragma unroll
      for (int m = 0; m < 4; ++m) {
        int row = wr * 64 + m * 16 + (lane & 15);
        int off = (row * 128 + ks * 64 + (lane >> 4) * 16) ^ swzb(row);
        a[m] = *(const short8*)((const char*)As + off);
      }
      #pragma unroll
      for (int n = 0; n < 4; ++n) {
        int c = wc * 64 + n * 16 + (lane & 15);
        int off = (c * 128 + ks * 64 + (lane >> 4) * 16) ^ swzb(c);
        b[n] = *(const short8*)((const char*)Bs + off);
      }
      #pragma unroll
      for (int m = 0; m < 4; ++m)
        #pragma unroll
        for (int n = 0; n < 4; ++n)
          acc[m][n] = __builtin_amdgcn_mfma_f32_16x16x32_bf16(a[m], b[n], acc[m][n], 0, 0, 0);
    }
  }

  #pragma unroll
  for (int m = 0; m < 4; ++m) {
    int rl0 = wr * 64 + m * 16 + ((lane >> 4) << 2);
    #pragma unroll
    for (int n = 0; n < 4; ++n) {
      int cl = wc * 64 + n * 16 + (lane & 15);
      int gc = col0 + cl;
      if (gc >= C_SZ) continue;
      #pragma unroll
      for (int r = 0; r < 4; ++r) {
        int rl = rl0 + r;
        float v = acc[m][n][r];
        v = fminf(fmaxf(v, -1.f + EPS_F), 1.f - EPS_F);
        float res = v * S_CONST;
        if (gc == lab_s[rl]) {
          float th = acosf(v) + ga_s[rl];
          th = fminf(fmaxf(th, EPS_F), PI_F - EPS_F);
          res = (cosf(th) - gadd_s[rl]) * S_CONST;
        }
        out[(size_t)(row0 + rl) * C_SZ + gc] = res;
      }
    }
  }
}

// ---------------- launch ----------------
extern "C" void kernel_launch(void* const* d_in, const int* in_sizes, int n_in,
                              void* d_out, int out_size, void* d_ws, size_t ws_size,
                              hipStream_t stream) {
  const float* emb   = (const float*)d_in[0];
  const float* norms = (const float*)d_in[1];
  const int*   label = (const int*)d_in[2];
  const float* kmat  = (const float*)d_in[3];
  float* out = (float*)d_out;

  // fast-path ws layout:
  //   [0, 283136)          invn  float[PAD_C]
  //   [283136, 285184)     ga    float[512]
  //   [285184, 287232)     gadd  float[512]
  //   [287232, 811520)     Abf   bf16[512*512]
  //   [811520, 73294336)   BT    bf16[PAD_C][512]
  const size_t NEED_FAST = 73294336;
  char* ws = (char*)d_ws;
  float* invn = (float*)ws;
  float* ga   = (float*)(ws + 283136);
  float* gadd = (float*)(ws + 285184);
  unsigned short* abf = (unsigned short*)(ws + 287232);
  unsigned short* bt  = (unsigned short*)(ws + 811520);

  k_stats<<<1, 512, 0, stream>>>(norms, label, ga, gadd);
  k_cvtA<<<256, 256, 0, stream>>>(emb, abf);

  if (ws_size >= NEED_FAST) {
    k_prep<<<1106, 256, 0, stream>>>(kmat, invn, bt);
    k_gemm_fast<<<2212, 256, 0, stream>>>(abf, bt, invn, label, ga, gadd, out);
  } else {
    k_colnorm<<<1106, 256, 0, stream>>>(kmat, invn);
    k_gemm_fb<<<2212, 256, 0, stream>>>(abf, kmat, invn, label, ga, gadd, out);
  }
}

// Round 4
// 150.424 us; speedup vs baseline: 1.0281x; 1.0281x over previous
//
#include <hip/hip_runtime.h>
#include <hip/hip_bf16.h>
#include <cstdint>
#include <cstddef>
#include <math.h>

#define B_SZ 512
#define E_SZ 512
#define C_SZ 70722
#define BN 64
#define NBLK 1106            // ceil(70722/64)
#define M_MARGIN 0.4f
#define H_CONST 0.333f
#define S_CONST 64.0f
#define EPS_F 1e-3f
#define PI_F 3.14159265358979323846f

typedef __attribute__((ext_vector_type(8))) short short8;
typedef __attribute__((ext_vector_type(4))) float f32x4;

// ---------------- helpers ----------------

__device__ __forceinline__ unsigned short f2bf(float x) {
  __hip_bfloat16 h = __float2bfloat16(x);
  unsigned short u;
  __builtin_memcpy(&u, &h, 2);
  return u;
}

__device__ __forceinline__ void gload_lds16(const void* g, void* l) {
  __builtin_amdgcn_global_load_lds(
      (const __attribute__((address_space(1))) unsigned int*)g,
      (__attribute__((address_space(3))) unsigned int*)l, 16, 0, 0);
}

// ---------------- kernel 1: per-row margin stats ----------------
__global__ void k_stats(const float* __restrict__ norms, const int* __restrict__ label,
                        float* __restrict__ ga, float* __restrict__ gadd) {
  __shared__ float sn[B_SZ];
  __shared__ int lab[B_SZ];
  __shared__ float redA[8], redB[8];
  __shared__ float sh_std;

  int t = threadIdx.x;
  float v = norms[t];
  v = fminf(fmaxf(v, 1e-3f), 100.0f);
  sn[t] = v;
  lab[t] = label[t];

  float s1 = v, s2 = v * v;
  #pragma unroll
  for (int o = 32; o > 0; o >>= 1) {
    s1 += __shfl_down(s1, o);
    s2 += __shfl_down(s2, o);
  }
  if ((t & 63) == 0) { redA[t >> 6] = s1; redB[t >> 6] = s2; }
  __syncthreads();
  if (t == 0) {
    float a = 0.f, b = 0.f;
    #pragma unroll
    for (int i = 0; i < 8; ++i) { a += redA[i]; b += redB[i]; }
    float mean = a / (float)B_SZ;
    float var = (b - (float)B_SZ * mean * mean) / (float)(B_SZ - 1);
    sh_std = sqrtf(fmaxf(var, 0.f));
  }
  __syncthreads();
  float stdv = sh_std;

  int myl = lab[t];
  float s = 0.f, cnt = 0.f;
  for (int j = 0; j < B_SZ; ++j) {
    bool m = (lab[j] == myl);
    s += m ? sn[j] : 0.f;
    cnt += m ? 1.f : 0.f;
  }
  float gm = s / fmaxf(cnt, 1.f);
  float ms = (v - gm) / (stdv + EPS_F) * H_CONST;
  ms = fminf(fmaxf(ms, -1.f), 1.f);
  ga[t] = -M_MARGIN * ms;
  gadd[t] = M_MARGIN + M_MARGIN * ms;
}

// ---------------- kernel 2: emb fp32 -> bf16 ----------------
__global__ void k_cvtA(const float* __restrict__ emb, unsigned short* __restrict__ abf) {
  int i = (blockIdx.x * 256 + threadIdx.x) * 4;
  float4 f = *(const float4*)(emb + i);
  unsigned short u0 = f2bf(f.x), u1 = f2bf(f.y), u2 = f2bf(f.z), u3 = f2bf(f.w);
  unsigned long long pk = (unsigned long long)u0 | ((unsigned long long)u1 << 16) |
                          ((unsigned long long)u2 << 32) | ((unsigned long long)u3 << 48);
  *(unsigned long long*)(abf + i) = pk;
}

// ---------------- kernel 3: fully-fused GEMM + colnorm + epilogue ----------------
// Block: M=512 (all rows) x N=64 cols, K=512 full. 512 thr = 8 waves, wave tile 64x64.
// A: bf16, global_load_lds, slot-XOR-swizzled (sigma = (row&15)>>2).
// B: fp32 coalesced row loads -> sumsq -> 4x4 shfl transpose -> bf16 -> ds_write_b64
//    into col-major Bs with the SAME sigma = (c&15)>>2 (lane-pure -> k-perms cancel).
// invn computed in-block from sumsq; applied with margin epilogue.
__launch_bounds__(512, 4)
__global__ void k_gemm_full(const unsigned short* __restrict__ Abf,  // [512][512] bf16
                            const float* __restrict__ Kmat,          // [512][C]
                            const int* __restrict__ label,
                            const float* __restrict__ ga,
                            const float* __restrict__ gadd,
                            float* __restrict__ out) {
  __shared__ __align__(16) unsigned short As[512 * 32];    // 32 KB, [row][32k]
  __shared__ __align__(16) unsigned short Bs[2][BN * 32];  // 2 x 4 KB, [col][32k]
  __shared__ float red[8][BN];
  __shared__ float invn_s[BN];
  __shared__ int lab_s[512];

  const int tid = threadIdx.x;
  const int w = tid >> 6;          // wave 0..7
  const int lane = tid & 63;
  const int q = lane >> 4;         // 0..3
  const int l15 = lane & 15;

  const int c0 = blockIdx.x * BN;
  const bool edge = (c0 + BN > C_SZ);

  lab_s[tid] = label[tid];

  // ---- B staging roles ----
  const int r_loc = tid >> 4;                 // 0..31 : k-row within tile (= w*4+q)
  const int bcol = c0 + (l15 << 2);           // 4-col chunk base
  // post-transpose: this thread owns col cT, k = 4w..4w+3
  const int cT = (l15 << 2) + q;
  const int sigT = l15 & 3;                   // (cT&15)>>2
  char* const bwr = (char*)&Bs[0][0] + cT * 64 + (((w >> 1) ^ sigT) & 3) * 16 + ((w & 1) << 3);

  // ---- A staging (per-wave 4 x gload_lds, 16 rows x 64B each) ----
  const int arow_l = lane >> 2;               // 0..15
  const int acg = (lane & 3) ^ q;             // pre-swizzled source chunk
  char* const adst = (char*)As + (w * 64) * 64;  // wave-uniform base (rows w*64..)

  // ---- fragment LDS byte offsets ----
  const int sfrag = l15 >> 2;
  int offA[4], offB[4];
  #pragma unroll
  for (int m = 0; m < 4; ++m) {
    int row = w * 64 + m * 16 + l15;
    offA[m] = row * 64 + ((q ^ sfrag) & 3) * 16;
  }
  #pragma unroll
  for (int n = 0; n < 4; ++n) {
    int c = n * 16 + l15;
    offB[n] = c * 64 + ((q ^ sfrag) & 3) * 16;
  }

  f32x4 acc[4][4];
  #pragma unroll
  for (int m = 0; m < 4; ++m)
    #pragma unroll
    for (int n = 0; n < 4; ++n)
      acc[m][n] = f32x4{0.f, 0.f, 0.f, 0.f};

  float ss0 = 0.f, ss1 = 0.f, ss2 = 0.f, ss3 = 0.f;

  // B load helper (row kb+r_loc, cols bcol..bcol+3)
#define BLOAD(bv, kb)                                                        \
  {                                                                          \
    const float* src = Kmat + (size_t)((kb) + r_loc) * C_SZ + bcol;          \
    if (!edge) {                                                             \
      bv = *(const float4*)src;                                              \
    } else {                                                                 \
      bv.x = (bcol + 0 < C_SZ) ? src[0] : 0.f;                               \
      bv.y = (bcol + 1 < C_SZ) ? src[1] : 0.f;                               \
      bv.z = (bcol + 2 < C_SZ) ? src[2] : 0.f;                               \
      bv.w = (bcol + 3 < C_SZ) ? src[3] : 0.f;                               \
    }                                                                        \
  }

  // sumsq + 4x4 transpose (lanes l, l^16, l^32, l^48) + bf16 pack + LDS write
#define BXPOSE_WRITE(bv, buf)                                                \
  {                                                                          \
    ss0 += bv.x * bv.x; ss1 += bv.y * bv.y;                                  \
    ss2 += bv.z * bv.z; ss3 += bv.w * bv.w;                                  \
    bool h32 = (lane & 32) != 0;                                             \
    float t2 = h32 ? bv.x : bv.z;                                            \
    float t3 = h32 ? bv.y : bv.w;                                            \
    float x2 = __shfl_xor(t2, 32);                                           \
    float x3 = __shfl_xor(t3, 32);                                           \
    float u0 = h32 ? x2 : bv.x;                                              \
    float u1 = h32 ? x3 : bv.y;                                              \
    float u2 = h32 ? bv.z : x2;                                              \
    float u3 = h32 ? bv.w : x3;                                              \
    bool h16 = (lane & 16) != 0;                                             \
    float s0 = h16 ? u0 : u1;                                                \
    float s1 = h16 ? u2 : u3;                                                \
    float z0 = __shfl_xor(s0, 16);                                           \
    float z1 = __shfl_xor(s1, 16);                                           \
    float y0 = h16 ? z0 : u0;                                                \
    float y1 = h16 ? u1 : z0;                                                \
    float y2 = h16 ? z1 : u2;                                                \
    float y3 = h16 ? u3 : z1;                                                \
    unsigned long long pk = (unsigned long long)f2bf(y0) |                   \
                            ((unsigned long long)f2bf(y1) << 16) |           \
                            ((unsigned long long)f2bf(y2) << 32) |           \
                            ((unsigned long long)f2bf(y3) << 48);            \
    *(unsigned long long*)(bwr + (buf) * 4096) = pk;                         \
  }

#define ASTAGE(kb)                                                           \
  {                                                                          \
    _Pragma("unroll")                                                        \
    for (int rr = 0; rr < 4; ++rr) {                                         \
      int r = w * 64 + rr * 16 + arow_l;                                     \
      gload_lds16(Abf + (size_t)r * 512 + (kb) + acg * 8, adst + rr * 1024); \
    }                                                                        \
  }

  // ---- prologue: tile 0 ----
  ASTAGE(0)
  {
    float4 bv;
    BLOAD(bv, 0)
    BXPOSE_WRITE(bv, 0)
  }
  __syncthreads();   // drains vmcnt (A staged) + lgkm (B written)

  // ---- main loop ----
  for (int kt = 0; kt < 16; ++kt) {
    const int cur = kt & 1;

    float4 bv;
    if (kt < 15) BLOAD(bv, (kt + 1) * 32)    // issue early: covered by MFMA phase

    short8 a[4], b[4];
    const char* pB = (const char*)&Bs[0][0] + cur * 4096;
    #pragma unroll
    for (int m = 0; m < 4; ++m) a[m] = *(const short8*)((const char*)As + offA[m]);
    #pragma unroll
    for (int n = 0; n < 4; ++n) b[n] = *(const short8*)(pB + offB[n]);

    #pragma unroll
    for (int m = 0; m < 4; ++m)
      #pragma unroll
      for (int n = 0; n < 4; ++n)
        acc[m][n] = __builtin_amdgcn_mfma_f32_16x16x32_bf16(a[m], b[n], acc[m][n], 0, 0, 0);

    __syncthreads();   // all waves done reading As(kt) & Bs[cur]; B-load drained

    if (kt < 15) {
      ASTAGE((kt + 1) * 32)
      BXPOSE_WRITE(bv, cur ^ 1)
    }
    __syncthreads();   // drains vmcnt (A staged) + lgkm (B written) -> published
  }
#undef BLOAD
#undef BXPOSE_WRITE
#undef ASTAGE

  // ---- column norms ----
  ss0 += __shfl_xor(ss0, 16); ss0 += __shfl_xor(ss0, 32);
  ss1 += __shfl_xor(ss1, 16); ss1 += __shfl_xor(ss1, 32);
  ss2 += __shfl_xor(ss2, 16); ss2 += __shfl_xor(ss2, 32);
  ss3 += __shfl_xor(ss3, 16); ss3 += __shfl_xor(ss3, 32);
  if (lane < 16) {
    red[w][l15 * 4 + 0] = ss0;
    red[w][l15 * 4 + 1] = ss1;
    red[w][l15 * 4 + 2] = ss2;
    red[w][l15 * 4 + 3] = ss3;
  }
  __syncthreads();
  if (tid < BN) {
    float s = 0.f;
    #pragma unroll
    for (int r = 0; r < 8; ++r) s += red[r][tid];
    invn_s[tid] = (s > 0.f) ? rsqrtf(s) : 0.f;
  }
  __syncthreads();

  // ---- epilogue: scale by invn, clip, margin on label column ----
  float invc[4];
  #pragma unroll
  for (int n = 0; n < 4; ++n) invc[n] = invn_s[n * 16 + l15];

  #pragma unroll
  for (int m = 0; m < 4; ++m) {
    int grow0 = w * 64 + m * 16 + q * 4;
    #pragma unroll
    for (int n = 0; n < 4; ++n) {
      int gc = c0 + n * 16 + l15;
      if (gc >= C_SZ) continue;
      #pragma unroll
      for (int r = 0; r < 4; ++r) {
        int grow = grow0 + r;
        float v = acc[m][n][r] * invc[n];
        v = fminf(fmaxf(v, -1.f + EPS_F), 1.f - EPS_F);
        float res = v * S_CONST;
        if (gc == lab_s[grow]) {
          float th = acosf(v) + ga[grow];
          th = fminf(fmaxf(th, EPS_F), PI_F - EPS_F);
          res = (cosf(th) - gadd[grow]) * S_CONST;
        }
        out[(size_t)grow * C_SZ + gc] = res;
      }
    }
  }
}

// ---------------- launch ----------------
extern "C" void kernel_launch(void* const* d_in, const int* in_sizes, int n_in,
                              void* d_out, int out_size, void* d_ws, size_t ws_size,
                              hipStream_t stream) {
  const float* emb   = (const float*)d_in[0];
  const float* norms = (const float*)d_in[1];
  const int*   label = (const int*)d_in[2];
  const float* kmat  = (const float*)d_in[3];
  float* out = (float*)d_out;

  // ws layout: [0,2048) ga | [2048,4096) gadd | [4096, 4096+512K) Abf
  char* ws = (char*)d_ws;
  float* ga   = (float*)ws;
  float* gadd = (float*)(ws + 2048);
  unsigned short* abf = (unsigned short*)(ws + 4096);

  k_stats<<<1, 512, 0, stream>>>(norms, label, ga, gadd);
  k_cvtA<<<256, 256, 0, stream>>>(emb, abf);
  k_gemm_full<<<NBLK, 512, 0, stream>>>(abf, kmat, label, ga, gadd, out);
}